// Round 13
// baseline (2954.051 us; speedup 1.0000x reference)
//
#include <hip/hip_runtime.h>
#include <hip/hip_fp8.h>
#include <math.h>

#define B_ROWS 2048
#define D_K    2048
#define N_CLS  50257
#define BM     256
#define BN     256
#define BKB    64               // K-bytes per step (fp8)
#define NT     (D_K / BKB)      // 32 K-steps
#define GM     8                // 2048/256 m-tiles
#define GN     197              // ceil(50257/256) n-tiles
#define N_PAD  (GN * BN)        // 50432
#define NWG    (GM * GN)        // 1576 = 8*197 (bijective XCD swizzle)

typedef __attribute__((ext_vector_type(4)))  int   i32x4;
typedef __attribute__((ext_vector_type(8)))  int   i32x8;
typedef __attribute__((ext_vector_type(16))) float f32x16;

typedef __attribute__((address_space(1))) const void as1cv;
typedef __attribute__((address_space(3))) void       as3v;

__device__ __forceinline__ void glds16(const void* g, void* l) {
  __builtin_amdgcn_global_load_lds((as1cv*)g, (as3v*)l, 16, 0, 0);
}

__device__ __forceinline__ unsigned char f2q(float x) {
  __hip_fp8_e4m3 q(x);
  return *reinterpret_cast<unsigned char*>(&q);
}

// ---------- W: fp32 -> fp8 e4m3, scaled x128, zero-padded to N_PAD rows ----------
__global__ void conv_w_q(const float* __restrict__ W, unsigned char* __restrict__ Wq) {
  const size_t NU = (size_t)N_PAD * D_K / 8;
  const size_t stride = (size_t)gridDim.x * blockDim.x;
  for (size_t u = (size_t)blockIdx.x * blockDim.x + threadIdx.x; u < NU; u += stride) {
    const size_t e = u * 8;
    unsigned long long pk = 0ull;
    if ((e >> 11) < (size_t)N_CLS) {
      const float4 a = *(const float4*)(W + e);
      const float4 b = *(const float4*)(W + e + 4);
      const float v[8] = {a.x, a.y, a.z, a.w, b.x, b.y, b.z, b.w};
#pragma unroll
      for (int i = 0; i < 8; ++i)
        pk |= (unsigned long long)f2q(v[i] * 128.0f) << (8 * i);
    }
    *(unsigned long long*)(Wq + e) = pk;
  }
}

// ---------- E: fp32 -> fp8 e4m3 in FRAGMENT-MAJOR layout (verified R8) ----------
// dst = [R>>5][t][rd][lane = ((kb>>5)&1)*32 + (R&31)][kb&15]; the GEMM's
// A-fragment load (32-row block, tile t, half rd) is one coalesced 1-KB read.
__global__ void conv_e_q(const float* __restrict__ E, unsigned char* __restrict__ EqT) {
  const size_t NU = (size_t)B_ROWS * D_K / 8;
  const size_t stride = (size_t)gridDim.x * blockDim.x;
  for (size_t u = (size_t)blockIdx.x * blockDim.x + threadIdx.x; u < NU; u += stride) {
    const size_t R  = u >> 8;                 // row
    const int    kb = (int)(u & 255) * 8;     // k-byte offset
    const float4 a = *(const float4*)(E + R * D_K + kb);
    const float4 b = *(const float4*)(E + R * D_K + kb + 4);
    const float v[8] = {a.x, a.y, a.z, a.w, b.x, b.y, b.z, b.w};
    unsigned long long pk = 0ull;
#pragma unroll
    for (int i = 0; i < 8; ++i)
      pk |= (unsigned long long)f2q(v[i]) << (8 * i);
    const int t  = kb >> 6;
    const int lh = (kb >> 5) & 1;
    const int rd = (kb >> 4) & 1;
    const int bb = kb & 15;
    const size_t dst = (((size_t)(R >> 5) * NT + t) * 2 + rd) * 1024
                     + (size_t)(lh * 32 + (int)(R & 31)) * 16 + bb;
    *(unsigned long long*)(EqT + dst) = pk;
  }
}

// ---------- fused MX-fp8 GEMM + per-tile row stats ----------
// 256x256 tile, 8 waves (2m x 4n), per-wave 128x64 via 4x2 mfma_scale 32x32x64.
// A: direct global->VGPR from fragment-major EqT (L1/L2-served, 4x wn-shared).
// B: LDS double-buffer (2x16KB), prefetch-before-compute, 1 barrier/step (R10).
// (512,2) shell = R7's measured no-spill register regime.
__global__ __launch_bounds__(512, 2) void gemm_ce(
    const unsigned char* __restrict__ EqT,
    const unsigned char* __restrict__ Wq,
    const int* __restrict__ labels,
    float* __restrict__ pm, float* __restrict__ ps, float* __restrict__ pt,
    float* __restrict__ ly)
{
  __shared__ __align__(16) char lds[2 * 16384];
  // stats overlay (live only after the K-loop's final barrier):
  float (*s_m)[4] = (float (*)[4])(lds);
  float (*s_s)[4] = (float (*)[4])(lds + 4096);
  float (*s_t)[4] = (float (*)[4])(lds + 8192);

  const int tid  = threadIdx.x;
  const int wid  = tid >> 6;
  const int lane = tid & 63;
  const int wm   = wid >> 2;       // 0..1 -> 128-row block
  const int wn   = wid & 3;        // 0..3 -> 64-col block
  const int l31  = lane & 31;
  const int lh   = lane >> 5;

  // XCD-aware bijective swizzle (NWG = 8*197); 8 consecutive logicals share
  // the B panel and land on one XCD (L2 reuse).
  const int bid     = blockIdx.x;
  const int logical = (bid & 7) * (NWG / 8) + (bid >> 3);
  const int n_tile  = logical / GM;
  const int m_tile  = logical % GM;

  // ---- B staging: thread t writes dest q*8192 + t*16 -> row = q*128 + (t>>2),
  //      slot pos = t&3; content slot = (t&3) ^ ((row>>1)&3) = (t&3)^((t>>3)&3)
  const int gsw  = (((tid & 3) ^ ((tid >> 3) & 3)) << 4);
  const int srow = tid >> 2;
  const unsigned char* Bg = Wq + (size_t)(n_tile * BN + srow) * D_K + gsw;
  const int sdst = tid * 16;
  // +q -> +128 rows = +262144 B global; +K-step -> +64 B

  // ---- B fragment LDS offsets: row R = wn*64 + fj*32 + l31, slots (2lh+rd)^rmsk
  const int rmsk = (l31 >> 1) & 3;
  int offB[2][2];
#pragma unroll
  for (int fj = 0; fj < 2; ++fj)
#pragma unroll
    for (int rd = 0; rd < 2; ++rd)
      offB[fj][rd] = (wn * 64 + fj * 32 + l31) * 64 + (((lh * 2 + rd) ^ rmsk) << 4);

  // ---- A fragment global base (fragment-major EqT) ----
  const unsigned char* Ab = EqT
      + ((size_t)(m_tile * 8 + wm * 4) * NT) * 2048 + (size_t)lane * 16;
  // fa[fi] at tile t, half rd: Ab + ((fi*NT + t)*2 + rd)*1024

  f32x16 acc[4][2] = {};
  union FR { i32x8 v; i32x4 h[2]; };

#define STAGE(BUF, TT)                                                     \
  do {                                                                     \
    const unsigned char* _b = Bg + (size_t)(TT) * BKB;                     \
    char* _d = lds + (BUF) * 16384 + sdst;                                 \
    glds16(_b,          _d);                                               \
    glds16(_b + 262144, _d + 8192);                                        \
  } while (0)

  // prologue: stage B tile 0 into buf0, drain, sync
  STAGE(0, 0);
  __syncthreads();

  for (int t = 0; t < NT; ++t) {
    const char* Rb = lds + (t & 1) * 16384;

    FR fb[2], fa[4];
#pragma unroll
    for (int fj = 0; fj < 2; ++fj) {
      fb[fj].h[0] = *(const i32x4*)(Rb + offB[fj][0]);
      fb[fj].h[1] = *(const i32x4*)(Rb + offB[fj][1]);
    }
#pragma unroll
    for (int fi = 0; fi < 4; ++fi) {
      fa[fi].h[0] = *(const i32x4*)(Ab + ((size_t)(fi * NT + t) * 2 + 0) * 1024);
      fa[fi].h[1] = *(const i32x4*)(Ab + ((size_t)(fi * NT + t) * 2 + 1) * 1024);
    }
    if (t < NT - 1) STAGE((t + 1) & 1, t + 1);   // prefetch next B tile

#pragma unroll
    for (int fi = 0; fi < 4; ++fi)
#pragma unroll
      for (int fj = 0; fj < 2; ++fj)
        acc[fi][fj] = __builtin_amdgcn_mfma_scale_f32_32x32x64_f8f6f4(
            fa[fi].v, fb[fj].v, acc[fi][fj], 0, 0,
            0, 0x7F7F7F7F, 0, 0x7F7F7F7F);

    // end of step: implicit vmcnt(0)+lgkmcnt(0)+barrier drains the B prefetch
    // (and the fa loads, which had the whole step to land)
    __syncthreads();
  }
#undef STAGE

  // ---------- epilogue: per-row (max, sumexp, sum) + label gather ----------
  // C/D 32x32: col = lane&31, row = (reg&3) + 8*(reg>>2) + 4*(lane>>5)  [m74/m101]
  const float inv = 0.0078125f;   // 1/128 (undo W pre-scale)
  const int colb = n_tile * BN + wn * 64;
  const int c0_  = colb + l31;
  const int c1_  = c0_ + 32;
  const bool ok0 = c0_ < N_CLS;
  const bool ok1 = c1_ < N_CLS;

#pragma unroll
  for (int fi = 0; fi < 4; ++fi) {
#pragma unroll
    for (int reg = 0; reg < 16; ++reg) {
      const int rt  = wm * 128 + fi * 32 + (reg & 3) + 8 * (reg >> 2) + 4 * lh;
      const int row = m_tile * BM + rt;
      const float v0 = acc[fi][0][reg] * inv;
      const float v1 = acc[fi][1][reg] * inv;
      const int lab = labels[row];
      if (lab == c0_) ly[row] = v0;
      if (lab == c1_) ly[row] = v1;

      float mx = fmaxf(ok0 ? v0 : -INFINITY, ok1 ? v1 : -INFINITY);
      float sm = (ok0 ? v0 : 0.f) + (ok1 ? v1 : 0.f);
#pragma unroll
      for (int d = 1; d < 32; d <<= 1) {
        mx = fmaxf(mx, __shfl_xor(mx, d));
        sm += __shfl_xor(sm, d);
      }
      float se = (ok0 ? __expf(v0 - mx) : 0.f) + (ok1 ? __expf(v1 - mx) : 0.f);
#pragma unroll
      for (int d = 1; d < 32; d <<= 1) se += __shfl_xor(se, d);

      if (l31 == 0) { s_m[rt][wn] = mx; s_s[rt][wn] = se; s_t[rt][wn] = sm; }
    }
  }
  __syncthreads();
  if (tid < BM) {
    float M = -INFINITY;
#pragma unroll
    for (int g = 0; g < 4; ++g) M = fmaxf(M, s_m[tid][g]);
    float S = 0.f, T = 0.f;
#pragma unroll
    for (int g = 0; g < 4; ++g) {
      S += s_s[tid][g] * __expf(s_m[tid][g] - M);
      T += s_t[tid][g];
    }
    const size_t o = (size_t)n_tile * B_ROWS + m_tile * BM + tid;
    pm[o] = M; ps[o] = S; pt[o] = T;
  }
}

// ---------- final combine: GN partials per row -> loss ----------
__global__ void ce_reduce(const float* __restrict__ pm, const float* __restrict__ ps,
                          const float* __restrict__ pt, const float* __restrict__ ly,
                          float* __restrict__ out)
{
  const int tid = threadIdx.x;
  const int row = blockIdx.x * blockDim.x + tid;
  float M = -INFINITY, S = 0.f, T = 0.f;
  for (int nt = 0; nt < GN; ++nt) {
    const size_t o = (size_t)nt * B_ROWS + row;
    const float m = pm[o], s = ps[o], t = pt[o];
    const float Mn = fmaxf(M, m);
    S = S * __expf(M - Mn) + s * __expf(m - Mn);
    M = Mn;
    T += t;
  }
  const float lse = M + logf(S);
  float per = lse - 0.9f * ly[row] - 0.1f * (T * (1.0f / (float)N_CLS));
#pragma unroll
  for (int d = 1; d < 64; d <<= 1) per += __shfl_xor(per, d);
  __shared__ float red[4];
  if ((tid & 63) == 0) red[tid >> 6] = per;
  __syncthreads();
  if (tid == 0)
    atomicAdd(out, (red[0] + red[1] + red[2] + red[3]) * (1.0f / B_ROWS));
}

extern "C" void kernel_launch(void* const* d_in, const int* in_sizes, int n_in,
                              void* d_out, int out_size, void* d_ws, size_t ws_size,
                              hipStream_t stream)
{
  const float* E      = (const float*)d_in[0];
  const int*   labels = (const int*)  d_in[1];
  const float* W      = (const float*)d_in[2];
  float* out = (float*)d_out;

  char* ws = (char*)d_ws;
  unsigned char* Wq = (unsigned char*)ws;
  size_t off = (size_t)N_PAD * D_K;                // 103,284,736 B
  unsigned char* EqT = (unsigned char*)(ws + off);
  off += (size_t)B_ROWS * D_K;                     // + 4,194,304 B
  float* pm = (float*)(ws + off); off += (size_t)GN * B_ROWS * 4;
  float* ps = (float*)(ws + off); off += (size_t)GN * B_ROWS * 4;
  float* pt = (float*)(ws + off); off += (size_t)GN * B_ROWS * 4;
  float* ly = (float*)(ws + off);                  // total ~112 MB

  hipMemsetAsync(d_out, 0, sizeof(float), stream);
  conv_w_q<<<dim3(2048), dim3(256), 0, stream>>>(W, Wq);
  conv_e_q<<<dim3(512),  dim3(256), 0, stream>>>(E, EqT);
  gemm_ce<<<dim3(NWG), dim3(512), 0, stream>>>(EqT, Wq, labels, pm, ps, pt, ly);
  ce_reduce<<<dim3(B_ROWS / 256), dim3(256), 0, stream>>>(pm, ps, pt, ly, out);
}

// Round 14
// 2719.604 us; speedup vs baseline: 1.0862x; 1.0862x over previous
//
#include <hip/hip_runtime.h>
#include <hip/hip_fp8.h>
#include <math.h>

#define B_ROWS 2048
#define D_K    2048
#define N_CLS  50257
#define BM     256
#define BN     256
#define BKB    64               // K-bytes per step (fp8)
#define NT     (D_K / BKB)      // 32 K-steps
#define GM     8                // 2048/256 m-tiles
#define GN     197              // ceil(50257/256) n-tiles
#define N_PAD  (GN * BN)        // 50432
#define NWG    (GM * GN)        // 1576 = 8*197 (bijective XCD swizzle)

// LDS: DOUBLE buffer, 32KB each. Buffer b at b*32768:
//   A [256 rows][64 B] at +0 (16KB), B [256 rows][64 B] at +16384 (16KB).
// 16-B slot swizzle within each 64-B row: position p = content_slot ^ ((row>>1)&3).
// Stats (12KB) OVERLAY buffer 0 — live only after the K-loop's final barrier.
#define ABY    16384
#define BUFB   32768

typedef __attribute__((ext_vector_type(4)))  int   i32x4;
typedef __attribute__((ext_vector_type(8)))  int   i32x8;
typedef __attribute__((ext_vector_type(16))) float f32x16;

typedef __attribute__((address_space(1))) const void as1cv;
typedef __attribute__((address_space(3))) void       as3v;

__device__ __forceinline__ void glds16(const void* g, void* l) {
  __builtin_amdgcn_global_load_lds((as1cv*)g, (as3v*)l, 16, 0, 0);
}

__device__ __forceinline__ unsigned char f2q(float x) {
  __hip_fp8_e4m3 q(x);
  return *reinterpret_cast<unsigned char*>(&q);
}

// ---------- W: fp32 -> fp8 e4m3, scaled x128, zero-padded to N_PAD rows ----------
__global__ void conv_w_q(const float* __restrict__ W, unsigned char* __restrict__ Wq) {
  const size_t NU = (size_t)N_PAD * D_K / 8;
  const size_t stride = (size_t)gridDim.x * blockDim.x;
  for (size_t u = (size_t)blockIdx.x * blockDim.x + threadIdx.x; u < NU; u += stride) {
    const size_t e = u * 8;
    unsigned long long pk = 0ull;
    if ((e >> 11) < (size_t)N_CLS) {
      const float4 a = *(const float4*)(W + e);
      const float4 b = *(const float4*)(W + e + 4);
      const float v[8] = {a.x, a.y, a.z, a.w, b.x, b.y, b.z, b.w};
#pragma unroll
      for (int i = 0; i < 8; ++i)
        pk |= (unsigned long long)f2q(v[i] * 128.0f) << (8 * i);
    }
    *(unsigned long long*)(Wq + e) = pk;
  }
}

// ---------- E: fp32 -> fp8 e4m3, row-major ----------
__global__ void conv_e_q(const float* __restrict__ E, unsigned char* __restrict__ Eq) {
  const size_t NU = (size_t)B_ROWS * D_K / 8;
  const size_t stride = (size_t)gridDim.x * blockDim.x;
  for (size_t u = (size_t)blockIdx.x * blockDim.x + threadIdx.x; u < NU; u += stride) {
    const size_t e = u * 8;
    const float4 a = *(const float4*)(E + e);
    const float4 b = *(const float4*)(E + e + 4);
    const float v[8] = {a.x, a.y, a.z, a.w, b.x, b.y, b.z, b.w};
    unsigned long long pk = 0ull;
#pragma unroll
    for (int i = 0; i < 8; ++i)
      pk |= (unsigned long long)f2q(v[i]) << (8 * i);
    *(unsigned long long*)(Eq + e) = pk;
  }
}

// ---------- fused MX-fp8 GEMM + per-tile row stats ----------
// 256x256 tile, 8 waves (2m x 4n), per-wave 128x64 via 4x2 mfma_scale 32x32x64.
// R7's (512,2) no-spill shell + LDS-sourced operands; R10's loop
// (prefetch-before-compute, single __syncthreads/step); 64KB LDS -> 2 blocks/CU.
__global__ __launch_bounds__(512, 2) void gemm_ce(
    const unsigned char* __restrict__ Eq,
    const unsigned char* __restrict__ Wq,
    const int* __restrict__ labels,
    float* __restrict__ pm, float* __restrict__ ps, float* __restrict__ pt,
    float* __restrict__ ly)
{
  __shared__ __align__(16) char lds[2 * BUFB];
  // stats overlay (live only after the K-loop's final barrier):
  float (*s_m)[4] = (float (*)[4])(lds);
  float (*s_s)[4] = (float (*)[4])(lds + 4096);
  float (*s_t)[4] = (float (*)[4])(lds + 8192);

  const int tid  = threadIdx.x;
  const int wid  = tid >> 6;
  const int lane = tid & 63;
  const int wm   = wid >> 2;       // 0..1 -> 128-row block
  const int wn   = wid & 3;        // 0..3 -> 64-col block
  const int l31  = lane & 31;
  const int lh   = lane >> 5;

  // XCD-aware bijective swizzle (NWG = 8*197)
  const int bid     = blockIdx.x;
  const int logical = (bid & 7) * (NWG / 8) + (bid >> 3);
  const int n_tile  = logical / GM;
  const int m_tile  = logical % GM;

  // ---- staging (R7 verbatim): dest = q*8192 + wid*1024 + lane*16
  //      row = q*128 + wid*16 + (lane>>2); slot pos = lane&3
  //      content slot = (lane&3) ^ ((row>>1)&3) = (lane&3) ^ ((lane>>3)&3)
  const int gsw  = (((lane & 3) ^ ((lane >> 3) & 3)) << 4);
  const int srow = wid * 16 + (lane >> 2);
  const unsigned char* Ag = Eq + (size_t)(m_tile * BM + srow) * D_K + gsw;
  const unsigned char* Bg = Wq + (size_t)(n_tile * BN + srow) * D_K + gsw;
  const int sdst = wid * 1024 + lane * 16;
  // +q -> +128 rows = +262144 B global; +K-step -> +64 B

  // ---- fragment read offsets (R7 verbatim): row R = base + l31,
  //      k-bytes lh*32.. -> content slots 2lh,2lh+1; pos = slot ^ ((l31>>1)&3)
  const int rmsk = (l31 >> 1) & 3;
  int offA[4][2], offB[2][2];
#pragma unroll
  for (int fi = 0; fi < 4; ++fi)
#pragma unroll
    for (int rd = 0; rd < 2; ++rd)
      offA[fi][rd] = (wm * 128 + fi * 32 + l31) * 64 + (((lh * 2 + rd) ^ rmsk) << 4);
#pragma unroll
  for (int fj = 0; fj < 2; ++fj)
#pragma unroll
    for (int rd = 0; rd < 2; ++rd)
      offB[fj][rd] = ABY + (wn * 64 + fj * 32 + l31) * 64 + (((lh * 2 + rd) ^ rmsk) << 4);

  f32x16 acc[4][2] = {};
  union FR { i32x8 v; i32x4 h[2]; };

#define STAGE(BUF, TT)                                                     \
  do {                                                                     \
    const unsigned char* _a = Ag + (size_t)(TT) * BKB;                     \
    const unsigned char* _b = Bg + (size_t)(TT) * BKB;                     \
    char* _d = lds + (BUF) * BUFB + sdst;                                  \
    glds16(_a,          _d);                                               \
    glds16(_a + 262144, _d + 8192);                                        \
    glds16(_b,          _d + ABY);                                         \
    glds16(_b + 262144, _d + ABY + 8192);                                  \
  } while (0)

  // prologue: stage tile 0 into buf0, drain, sync
  STAGE(0, 0);
  __syncthreads();

  for (int t = 0; t < NT; ++t) {
    const char* Rb = lds + (t & 1) * BUFB;

    if (t < NT - 1) STAGE((t + 1) & 1, t + 1);   // prefetch next step

    FR fa[4], fb[2];
#pragma unroll
    for (int fj = 0; fj < 2; ++fj) {
      fb[fj].h[0] = *(const i32x4*)(Rb + offB[fj][0]);
      fb[fj].h[1] = *(const i32x4*)(Rb + offB[fj][1]);
    }
#pragma unroll
    for (int fi = 0; fi < 4; ++fi) {
      fa[fi].h[0] = *(const i32x4*)(Rb + offA[fi][0]);
      fa[fi].h[1] = *(const i32x4*)(Rb + offA[fi][1]);
    }

#pragma unroll
    for (int fi = 0; fi < 4; ++fi)
#pragma unroll
      for (int fj = 0; fj < 2; ++fj)
        acc[fi][fj] = __builtin_amdgcn_mfma_scale_f32_32x32x64_f8f6f4(
            fa[fi].v, fb[fj].v, acc[fi][fj], 0, 0,
            0, 0x7F7F7F7F, 0, 0x7F7F7F7F);

    // end of step: implicit vmcnt(0)+lgkmcnt(0)+barrier drains the prefetch
    __syncthreads();
  }
#undef STAGE

  // ---------- epilogue: per-row (max, sumexp, sum) + label gather ----------
  // C/D 32x32: col = lane&31, row = (reg&3) + 8*(reg>>2) + 4*(lane>>5)  [m74/m101]
  const float inv = 0.0078125f;   // 1/128 (undo W pre-scale)
  const int colb = n_tile * BN + wn * 64;
  const int c0_  = colb + l31;
  const int c1_  = c0_ + 32;
  const bool ok0 = c0_ < N_CLS;
  const bool ok1 = c1_ < N_CLS;

#pragma unroll
  for (int fi = 0; fi < 4; ++fi) {
#pragma unroll
    for (int reg = 0; reg < 16; ++reg) {
      const int rt  = wm * 128 + fi * 32 + (reg & 3) + 8 * (reg >> 2) + 4 * lh;
      const int row = m_tile * BM + rt;
      const float v0 = acc[fi][0][reg] * inv;
      const float v1 = acc[fi][1][reg] * inv;
      const int lab = labels[row];
      if (lab == c0_) ly[row] = v0;
      if (lab == c1_) ly[row] = v1;

      float mx = fmaxf(ok0 ? v0 : -INFINITY, ok1 ? v1 : -INFINITY);
      float sm = (ok0 ? v0 : 0.f) + (ok1 ? v1 : 0.f);
#pragma unroll
      for (int d = 1; d < 32; d <<= 1) {
        mx = fmaxf(mx, __shfl_xor(mx, d));
        sm += __shfl_xor(sm, d);
      }
      float se = (ok0 ? __expf(v0 - mx) : 0.f) + (ok1 ? __expf(v1 - mx) : 0.f);
#pragma unroll
      for (int d = 1; d < 32; d <<= 1) se += __shfl_xor(se, d);

      if (l31 == 0) { s_m[rt][wn] = mx; s_s[rt][wn] = se; s_t[rt][wn] = sm; }
    }
  }
  __syncthreads();
  if (tid < BM) {
    float M = -INFINITY;
#pragma unroll
    for (int g = 0; g < 4; ++g) M = fmaxf(M, s_m[tid][g]);
    float S = 0.f, T = 0.f;
#pragma unroll
    for (int g = 0; g < 4; ++g) {
      S += s_s[tid][g] * __expf(s_m[tid][g] - M);
      T += s_t[tid][g];
    }
    const size_t o = (size_t)n_tile * B_ROWS + m_tile * BM + tid;
    pm[o] = M; ps[o] = S; pt[o] = T;
  }
}

// ---------- final combine: GN partials per row -> loss ----------
__global__ void ce_reduce(const float* __restrict__ pm, const float* __restrict__ ps,
                          const float* __restrict__ pt, const float* __restrict__ ly,
                          float* __restrict__ out)
{
  const int tid = threadIdx.x;
  const int row = blockIdx.x * blockDim.x + tid;
  float M = -INFINITY, S = 0.f, T = 0.f;
  for (int nt = 0; nt < GN; ++nt) {
    const size_t o = (size_t)nt * B_ROWS + row;
    const float m = pm[o], s = ps[o], t = pt[o];
    const float Mn = fmaxf(M, m);
    S = S * __expf(M - Mn) + s * __expf(m - Mn);
    M = Mn;
    T += t;
  }
  const float lse = M + logf(S);
  float per = lse - 0.9f * ly[row] - 0.1f * (T * (1.0f / (float)N_CLS));
#pragma unroll
  for (int d = 1; d < 64; d <<= 1) per += __shfl_xor(per, d);
  __shared__ float red[4];
  if ((tid & 63) == 0) red[tid >> 6] = per;
  __syncthreads();
  if (tid == 0)
    atomicAdd(out, (red[0] + red[1] + red[2] + red[3]) * (1.0f / B_ROWS));
}

extern "C" void kernel_launch(void* const* d_in, const int* in_sizes, int n_in,
                              void* d_out, int out_size, void* d_ws, size_t ws_size,
                              hipStream_t stream)
{
  const float* E      = (const float*)d_in[0];
  const int*   labels = (const int*)  d_in[1];
  const float* W      = (const float*)d_in[2];
  float* out = (float*)d_out;

  char* ws = (char*)d_ws;
  unsigned char* Wq = (unsigned char*)ws;
  size_t off = (size_t)N_PAD * D_K;                // 103,284,736 B
  unsigned char* Eq = (unsigned char*)(ws + off);
  off += (size_t)B_ROWS * D_K;                     // + 4,194,304 B
  float* pm = (float*)(ws + off); off += (size_t)GN * B_ROWS * 4;
  float* ps = (float*)(ws + off); off += (size_t)GN * B_ROWS * 4;
  float* pt = (float*)(ws + off); off += (size_t)GN * B_ROWS * 4;
  float* ly = (float*)(ws + off);                  // total ~112 MB

  hipMemsetAsync(d_out, 0, sizeof(float), stream);
  conv_w_q<<<dim3(2048), dim3(256), 0, stream>>>(W, Wq);
  conv_e_q<<<dim3(512),  dim3(256), 0, stream>>>(E, Eq);
  gemm_ce<<<dim3(NWG), dim3(512), 0, stream>>>(Eq, Wq, labels, pm, ps, pt, ly);
  ce_reduce<<<dim3(B_ROWS / 256), dim3(256), 0, stream>>>(pm, ps, pt, ly, out);
}

// Round 15
// 1588.999 us; speedup vs baseline: 1.8591x; 1.7115x over previous
//
#include <hip/hip_runtime.h>
#include <hip/hip_fp8.h>
#include <math.h>

#define B_ROWS 2048
#define D_K    2048
#define N_CLS  50257
#define BM     128
#define BN     128
#define BKB    64               // K-bytes per step (fp8)
#define NT     (D_K / BKB)      // 32 K-steps
#define GM     16               // 2048/128 m-tiles
#define GN     393              // ceil(50257/128) n-tiles
#define N_PAD  (GN * BN)        // 50304
#define NWG    (GM * GN)        // 6288 = 8*786 (bijective XCD swizzle)

// LDS: TRIPLE buffer, 16KB each (distance-2 prefetch, counted vmcnt).
// Buffer b at b*16384: A [128 rows][64 B] at +0 (8KB), B at +8192 (8KB).
// 16-B slot swizzle within each 64-B row: position p = content_slot ^ ((row>>1)&3)
// (R5-verified conflict-free pattern). Stats (3KB) overlay buf0 after the loop.
#define BBY    8192
#define BUFB   16384

typedef __attribute__((ext_vector_type(4)))  int   i32x4;
typedef __attribute__((ext_vector_type(8)))  int   i32x8;
typedef __attribute__((ext_vector_type(16))) float f32x16;

typedef __attribute__((address_space(1))) const void as1cv;
typedef __attribute__((address_space(3))) void       as3v;

__device__ __forceinline__ void glds16(const void* g, void* l) {
  __builtin_amdgcn_global_load_lds((as1cv*)g, (as3v*)l, 16, 0, 0);
}

__device__ __forceinline__ unsigned char f2q(float x) {
  __hip_fp8_e4m3 q(x);
  return *reinterpret_cast<unsigned char*>(&q);
}

// ---------- W: fp32 -> fp8 e4m3, scaled x128, zero-padded to N_PAD rows ----------
__global__ void conv_w_q(const float* __restrict__ W, unsigned char* __restrict__ Wq) {
  const size_t NU = (size_t)N_PAD * D_K / 8;
  const size_t stride = (size_t)gridDim.x * blockDim.x;
  for (size_t u = (size_t)blockIdx.x * blockDim.x + threadIdx.x; u < NU; u += stride) {
    const size_t e = u * 8;
    unsigned long long pk = 0ull;
    if ((e >> 11) < (size_t)N_CLS) {
      const float4 a = *(const float4*)(W + e);
      const float4 b = *(const float4*)(W + e + 4);
      const float v[8] = {a.x, a.y, a.z, a.w, b.x, b.y, b.z, b.w};
#pragma unroll
      for (int i = 0; i < 8; ++i)
        pk |= (unsigned long long)f2q(v[i] * 128.0f) << (8 * i);
    }
    *(unsigned long long*)(Wq + e) = pk;
  }
}

// ---------- E: fp32 -> fp8 e4m3, row-major ----------
__global__ void conv_e_q(const float* __restrict__ E, unsigned char* __restrict__ Eq) {
  const size_t NU = (size_t)B_ROWS * D_K / 8;
  const size_t stride = (size_t)gridDim.x * blockDim.x;
  for (size_t u = (size_t)blockIdx.x * blockDim.x + threadIdx.x; u < NU; u += stride) {
    const size_t e = u * 8;
    const float4 a = *(const float4*)(E + e);
    const float4 b = *(const float4*)(E + e + 4);
    const float v[8] = {a.x, a.y, a.z, a.w, b.x, b.y, b.z, b.w};
    unsigned long long pk = 0ull;
#pragma unroll
    for (int i = 0; i < 8; ++i)
      pk |= (unsigned long long)f2q(v[i]) << (8 * i);
    *(unsigned long long*)(Eq + e) = pk;
  }
}

// ---------- fused MX-fp8 GEMM + per-tile row stats ----------
// 128x128 tile, 4 waves (2x2), per-wave 64x64 via 2x2 mfma_scale 32x32x64
// (acc = 64 regs: the never-spilled profile). 3-buffer LDS, prefetch distance 2,
// counted vmcnt(4) across raw barriers (loads stay in flight), 48KB -> 3 blocks/CU.
__global__ __launch_bounds__(256) void gemm_ce(
    const unsigned char* __restrict__ Eq,
    const unsigned char* __restrict__ Wq,
    const int* __restrict__ labels,
    float* __restrict__ pm, float* __restrict__ ps, float* __restrict__ pt,
    float* __restrict__ ly)
{
  __shared__ __align__(16) char lds[3 * BUFB];
  // stats overlay (live only after the K-loop's final barrier):
  float (*s_m)[2] = (float (*)[2])(lds);
  float (*s_s)[2] = (float (*)[2])(lds + 1024);
  float (*s_t)[2] = (float (*)[2])(lds + 2048);

  const int tid  = threadIdx.x;
  const int wid  = tid >> 6;
  const int lane = tid & 63;
  const int wm   = wid >> 1;       // 0..1 -> 64-row block
  const int wn   = wid & 1;        // 0..1 -> 64-col block
  const int l31  = lane & 31;
  const int lh   = lane >> 5;      // 0..1 -> k-half

  // XCD-aware bijective swizzle (NWG = 8*786); 16 consecutive logicals share
  // the B panel and land on one XCD.
  const int bid     = blockIdx.x;
  const int logical = (bid & 7) * (NWG / 8) + (bid >> 3);
  const int n_tile  = logical / GM;
  const int m_tile  = logical % GM;

  // ---- staging: thread t, part q -> dest byte q*4096 + t*16
  //      row = q*64 + (t>>2); slot position = t&3
  //      content slot = (t&3) ^ ((row>>1)&3) = (t&3) ^ ((t>>3)&3)  (q*32 ≡ 0 mod 4)
  const int gsw  = (((tid & 3) ^ ((tid >> 3) & 3)) << 4);
  const int srow = tid >> 2;
  const unsigned char* Ag = Eq + (size_t)(m_tile * BM + srow) * D_K + gsw;
  const unsigned char* Bg = Wq + (size_t)(n_tile * BN + srow) * D_K + gsw;
  const int sdst = tid * 16;
  // +q -> +64 rows = +131072 B global; +K-step -> +64 B

  // ---- fragment read offsets (32x32x64, R5-verified swizzle):
  //      row R = base + l31; k-bytes lh*32+rd*16 -> content slot lh*2+rd;
  //      position = slot ^ ((R>>1)&3) = slot ^ ((l31>>1)&3)  (bases ≡ 0 mod 8)
  const int rmsk = (l31 >> 1) & 3;
  int offA[2][2], offB[2][2];
#pragma unroll
  for (int fi = 0; fi < 2; ++fi)
#pragma unroll
    for (int rd = 0; rd < 2; ++rd)
      offA[fi][rd] = (wm * 64 + fi * 32 + l31) * 64 + (((lh * 2 + rd) ^ rmsk) << 4);
#pragma unroll
  for (int fj = 0; fj < 2; ++fj)
#pragma unroll
    for (int rd = 0; rd < 2; ++rd)
      offB[fj][rd] = BBY + (wn * 64 + fj * 32 + l31) * 64 + (((lh * 2 + rd) ^ rmsk) << 4);

  f32x16 acc[2][2] = {};
  union FR { i32x8 v; i32x4 h[2]; };

#define STAGE(BUF, TT)                                                     \
  do {                                                                     \
    const unsigned char* _a = Ag + (size_t)(TT) * BKB;                     \
    const unsigned char* _b = Bg + (size_t)(TT) * BKB;                     \
    char* _d = lds + (BUF) * BUFB + sdst;                                  \
    glds16(_a,          _d);                                               \
    glds16(_a + 131072, _d + 4096);                                        \
    glds16(_b,          _d + BBY);                                         \
    glds16(_b + 131072, _d + BBY + 4096);                                  \
  } while (0)

  // prologue: stage tiles 0,1 into bufs 0,1; wait for tile 0 only (keep 1 in flight)
  STAGE(0, 0);
  STAGE(1, 1);
  asm volatile("s_waitcnt vmcnt(4)" ::: "memory");
  __builtin_amdgcn_sched_barrier(0);
  __builtin_amdgcn_s_barrier();
  __builtin_amdgcn_sched_barrier(0);

  int c0 = 0, c1 = 1, c2 = 2;
  for (int t = 0; t < NT; ++t) {
    const char* Rb = lds + c0 * BUFB;

    if (t < NT - 2) STAGE(c2, t + 2);   // distance-2 prefetch

    FR fa[2], fb[2];
#pragma unroll
    for (int fi = 0; fi < 2; ++fi) {
      fa[fi].h[0] = *(const i32x4*)(Rb + offA[fi][0]);
      fa[fi].h[1] = *(const i32x4*)(Rb + offA[fi][1]);
    }
#pragma unroll
    for (int fj = 0; fj < 2; ++fj) {
      fb[fj].h[0] = *(const i32x4*)(Rb + offB[fj][0]);
      fb[fj].h[1] = *(const i32x4*)(Rb + offB[fj][1]);
    }

    __builtin_amdgcn_s_setprio(1);
#pragma unroll
    for (int fi = 0; fi < 2; ++fi)
#pragma unroll
      for (int fj = 0; fj < 2; ++fj)
        acc[fi][fj] = __builtin_amdgcn_mfma_scale_f32_32x32x64_f8f6f4(
            fa[fi].v, fb[fj].v, acc[fi][fj], 0, 0,
            0, 0x7F7F7F7F, 0, 0x7F7F7F7F);
    __builtin_amdgcn_s_setprio(0);

    // end of step: wait for stage(t+1) to land (keep stage(t+2)'s 4 loads in
    // flight across the barrier — counted vmcnt, never 0 until the tail).
    if (t < NT - 2) asm volatile("s_waitcnt vmcnt(4)" ::: "memory");
    else            asm volatile("s_waitcnt vmcnt(0)" ::: "memory");
    __builtin_amdgcn_sched_barrier(0);
    __builtin_amdgcn_s_barrier();
    __builtin_amdgcn_sched_barrier(0);

    const int tmp = c0; c0 = c1; c1 = c2; c2 = tmp;
  }
#undef STAGE

  // ---------- epilogue: per-row (max, sumexp, sum) + label gather ----------
  // C/D 32x32: col = lane&31, row = (reg&3) + 8*(reg>>2) + 4*(lane>>5)  [m74/m101]
  const float inv = 0.0078125f;   // 1/128 (undo W pre-scale)
  const int colb = n_tile * BN + wn * 64;
  const int c0_  = colb + l31;
  const int c1_  = c0_ + 32;
  const bool ok0 = c0_ < N_CLS;
  const bool ok1 = c1_ < N_CLS;

#pragma unroll
  for (int fi = 0; fi < 2; ++fi) {
#pragma unroll
    for (int reg = 0; reg < 16; ++reg) {
      const int rt  = wm * 64 + fi * 32 + (reg & 3) + 8 * (reg >> 2) + 4 * lh;
      const int row = m_tile * BM + rt;
      const float v0 = acc[fi][0][reg] * inv;
      const float v1 = acc[fi][1][reg] * inv;
      const int lab = labels[row];
      if (lab == c0_) ly[row] = v0;
      if (lab == c1_) ly[row] = v1;

      float mx = fmaxf(ok0 ? v0 : -INFINITY, ok1 ? v1 : -INFINITY);
      float sm = (ok0 ? v0 : 0.f) + (ok1 ? v1 : 0.f);
#pragma unroll
      for (int d = 1; d < 32; d <<= 1) {
        mx = fmaxf(mx, __shfl_xor(mx, d));
        sm += __shfl_xor(sm, d);
      }
      float se = (ok0 ? __expf(v0 - mx) : 0.f) + (ok1 ? __expf(v1 - mx) : 0.f);
#pragma unroll
      for (int d = 1; d < 32; d <<= 1) se += __shfl_xor(se, d);

      if (l31 == 0) { s_m[rt][wn] = mx; s_s[rt][wn] = se; s_t[rt][wn] = sm; }
    }
  }
  __syncthreads();
  if (tid < BM) {
    const float m0 = s_m[tid][0], m1 = s_m[tid][1];
    const float M = fmaxf(m0, m1);
    const float S = s_s[tid][0] * __expf(m0 - M) + s_s[tid][1] * __expf(m1 - M);
    const float T = s_t[tid][0] + s_t[tid][1];
    const size_t o = (size_t)n_tile * B_ROWS + m_tile * BM + tid;
    pm[o] = M; ps[o] = S; pt[o] = T;
  }
}

// ---------- final combine: GN partials per row -> loss ----------
__global__ void ce_reduce(const float* __restrict__ pm, const float* __restrict__ ps,
                          const float* __restrict__ pt, const float* __restrict__ ly,
                          float* __restrict__ out)
{
  const int tid = threadIdx.x;
  const int row = blockIdx.x * blockDim.x + tid;
  float M = -INFINITY, S = 0.f, T = 0.f;
  for (int nt = 0; nt < GN; ++nt) {
    const size_t o = (size_t)nt * B_ROWS + row;
    const float m = pm[o], s = ps[o], t = pt[o];
    const float Mn = fmaxf(M, m);
    S = S * __expf(M - Mn) + s * __expf(m - Mn);
    M = Mn;
    T += t;
  }
  const float lse = M + logf(S);
  float per = lse - 0.9f * ly[row] - 0.1f * (T * (1.0f / (float)N_CLS));
#pragma unroll
  for (int d = 1; d < 64; d <<= 1) per += __shfl_xor(per, d);
  __shared__ float red[4];
  if ((tid & 63) == 0) red[tid >> 6] = per;
  __syncthreads();
  if (tid == 0)
    atomicAdd(out, (red[0] + red[1] + red[2] + red[3]) * (1.0f / B_ROWS));
}

extern "C" void kernel_launch(void* const* d_in, const int* in_sizes, int n_in,
                              void* d_out, int out_size, void* d_ws, size_t ws_size,
                              hipStream_t stream)
{
  const float* E      = (const float*)d_in[0];
  const int*   labels = (const int*)  d_in[1];
  const float* W      = (const float*)d_in[2];
  float* out = (float*)d_out;

  char* ws = (char*)d_ws;
  unsigned char* Wq = (unsigned char*)ws;
  size_t off = (size_t)N_PAD * D_K;                // 103,022,592 B
  unsigned char* Eq = (unsigned char*)(ws + off);
  off += (size_t)B_ROWS * D_K;                     // + 4,194,304 B
  float* pm = (float*)(ws + off); off += (size_t)GN * B_ROWS * 4;
  float* ps = (float*)(ws + off); off += (size_t)GN * B_ROWS * 4;
  float* pt = (float*)(ws + off); off += (size_t)GN * B_ROWS * 4;
  float* ly = (float*)(ws + off);                  // total ~117 MB

  hipMemsetAsync(d_out, 0, sizeof(float), stream);
  conv_w_q<<<dim3(2048), dim3(256), 0, stream>>>(W, Wq);
  conv_e_q<<<dim3(512),  dim3(256), 0, stream>>>(E, Eq);
  gemm_ce<<<dim3(NWG), dim3(256), 0, stream>>>(Eq, Wq, labels, pm, ps, pt, ly);
  ce_reduce<<<dim3(B_ROWS / 256), dim3(256), 0, stream>>>(pm, ps, pt, ly, out);
}

// Round 16
// 420.008 us; speedup vs baseline: 7.0333x; 3.7833x over previous
//
#include <hip/hip_runtime.h>
#include <math.h>

#define B_ROWS 2048
#define D_K    2048
#define DKB    1024             // bytes per row at fp4 (0.5 B/elem)
#define N_CLS  50257
#define BM     128
#define BN     128
#define BKB    64               // K-BYTES per step = 128 elements
#define NT     16               // 2048 / 128 elements
#define GM     16               // 2048/128 m-tiles
#define GN     393              // ceil(50257/128) n-tiles
#define N_PAD  (GN * BN)        // 50304
#define NWG    (GM * GN)        // 6288 = 8*786 (bijective XCD swizzle)

// LDS: DOUBLE buffer, 16KB each. Buffer b at b*16384:
//   A [128 rows][64 B] at +0 (8KB), B [128 rows][64 B] at +8192 (8KB).
// 16-B slot swizzle within each 64-B row: position p = content_slot ^ ((row>>1)&3)
// (R5/R11-verified conflict-free). Stats (3KB) overlay buf0 after the loop.
#define BBY    8192
#define BUFB   16384

typedef __attribute__((ext_vector_type(4))) int   i32x4;
typedef __attribute__((ext_vector_type(8))) int   i32x8;
typedef __attribute__((ext_vector_type(4))) float f32x4;

typedef __attribute__((address_space(1))) const void as1cv;
typedef __attribute__((address_space(3))) void       as3v;

__device__ __forceinline__ void glds16(const void* g, void* l) {
  __builtin_amdgcn_global_load_lds((as1cv*)g, (as3v*)l, 16, 0, 0);
}

// ---- fp32 -> fp4 e2m1 (RNE on the 8-level grid), returns 4-bit code ----
__device__ __forceinline__ unsigned int q4(float x) {
  const unsigned int s = (x < 0.f) ? 8u : 0u;
  const float a = fabsf(x);
  unsigned int c;
  if      (a < 0.25f) c = 0;      // 0.0
  else if (a < 0.75f) c = 1;      // 0.5
  else if (a < 1.25f) c = 2;      // 1.0
  else if (a < 1.75f) c = 3;      // 1.5
  else if (a < 2.5f)  c = 4;      // 2.0
  else if (a < 3.5f)  c = 5;      // 3.0
  else if (a < 5.0f)  c = 6;      // 4.0
  else                c = 7;      // 6.0
  return s | c;
}

// ---------- W: fp32 -> fp4, scaled x128, zero-padded to N_PAD rows ----------
// 16 elements -> 8 output bytes per unit; element k -> byte k/2, nibble k&1.
__global__ void conv_w_q4(const float* __restrict__ W, unsigned char* __restrict__ Wq) {
  const size_t NU = (size_t)N_PAD * D_K / 16;
  const size_t stride = (size_t)gridDim.x * blockDim.x;
  for (size_t u = (size_t)blockIdx.x * blockDim.x + threadIdx.x; u < NU; u += stride) {
    const size_t e = u * 16;
    unsigned long long pk = 0ull;
    if ((e >> 11) < (size_t)N_CLS) {
#pragma unroll
      for (int g = 0; g < 4; ++g) {
        const float4 a = *(const float4*)(W + e + g * 4);
        pk |= (unsigned long long)q4(a.x * 128.0f) << (16 * g + 0);
        pk |= (unsigned long long)q4(a.y * 128.0f) << (16 * g + 4);
        pk |= (unsigned long long)q4(a.z * 128.0f) << (16 * g + 8);
        pk |= (unsigned long long)q4(a.w * 128.0f) << (16 * g + 12);
      }
    }
    *(unsigned long long*)(Wq + u * 8) = pk;
  }
}

// ---------- E: fp32 -> fp4, unscaled ----------
__global__ void conv_e_q4(const float* __restrict__ E, unsigned char* __restrict__ Eq) {
  const size_t NU = (size_t)B_ROWS * D_K / 16;
  const size_t stride = (size_t)gridDim.x * blockDim.x;
  for (size_t u = (size_t)blockIdx.x * blockDim.x + threadIdx.x; u < NU; u += stride) {
    const size_t e = u * 16;
    unsigned long long pk = 0ull;
#pragma unroll
    for (int g = 0; g < 4; ++g) {
      const float4 a = *(const float4*)(E + e + g * 4);
      pk |= (unsigned long long)q4(a.x) << (16 * g + 0);
      pk |= (unsigned long long)q4(a.y) << (16 * g + 4);
      pk |= (unsigned long long)q4(a.z) << (16 * g + 8);
      pk |= (unsigned long long)q4(a.w) << (16 * g + 12);
    }
    *(unsigned long long*)(Eq + u * 8) = pk;
  }
}

// ---------- fused MX-fp4 GEMM + per-tile row stats ----------
// R10 structure verbatim (prefetch-before-compute, 1 __syncthreads/step,
// never-spilled f32x4 acc profile), data in fp4: cbsz=blgp=4 (e2m1),
// fragments = 1 b128/frag (HW reads v[0:3] only), uniform MX scale = 1.0.
__global__ __launch_bounds__(256) void gemm_ce(
    const unsigned char* __restrict__ Eq,
    const unsigned char* __restrict__ Wq,
    const int* __restrict__ labels,
    float* __restrict__ pm, float* __restrict__ ps, float* __restrict__ pt,
    float* __restrict__ ly)
{
  __shared__ __align__(16) char lds[2 * BUFB];
  // stats overlay (live only after the K-loop's final barrier):
  float (*s_m)[2] = (float (*)[2])(lds);
  float (*s_s)[2] = (float (*)[2])(lds + 1024);
  float (*s_t)[2] = (float (*)[2])(lds + 2048);

  const int tid  = threadIdx.x;
  const int wid  = tid >> 6;
  const int lane = tid & 63;
  const int wm   = wid >> 1;       // 0..1 -> 64-row block
  const int wn   = wid & 1;        // 0..1 -> 64-col block
  const int l16  = lane & 15;
  const int lhi  = lane >> 4;      // 0..3 -> 32-element k-chunk (16 B at fp4)

  // XCD-aware bijective swizzle (NWG = 8*786)
  const int bid     = blockIdx.x;
  const int logical = (bid & 7) * (NWG / 8) + (bid >> 3);
  const int n_tile  = logical / GM;   // 16 consecutive logicals share B panel
  const int m_tile  = logical % GM;

  // ---- staging: thread t, part q -> dest byte q*4096 + t*16
  //      row = q*64 + (t>>2); slot position = t&3
  //      content slot = (t&3) ^ ((row>>1)&3) = (t&3) ^ ((t>>3)&3)
  const int gsw  = (((tid & 3) ^ ((tid >> 3) & 3)) << 4);
  const int srow = tid >> 2;
  const unsigned char* Ag = Eq + (size_t)(m_tile * BM + srow) * DKB + gsw;
  const unsigned char* Bg = Wq + (size_t)(n_tile * BN + srow) * DKB + gsw;
  const int sdst = tid * 16;
  // +q -> +64 rows = +65536 B global; +K-step -> +64 B

  // ---- fragment read offsets: row R = base + l16 (64-B rows), content slot
  //      = lhi (elements lhi*32..+31 = bytes lhi*16..+15), position = lhi ^ ((R>>1)&3)
  const int rmsk = (l16 >> 1) & 3;
  const int psw  = (lhi ^ rmsk) << 4;
  int offA[4], offB[4];
#pragma unroll
  for (int fi = 0; fi < 4; ++fi)
    offA[fi] = (wm * 64 + fi * 16 + l16) * 64 + psw;
#pragma unroll
  for (int fj = 0; fj < 4; ++fj)
    offB[fj] = BBY + (wn * 64 + fj * 16 + l16) * 64 + psw;

  f32x4 acc[4][4] = {};

#define STAGE(BUF, TT)                                                     \
  do {                                                                     \
    const unsigned char* _a = Ag + (size_t)(TT) * BKB;                     \
    const unsigned char* _b = Bg + (size_t)(TT) * BKB;                     \
    char* _d = lds + (BUF) * BUFB + sdst;                                  \
    glds16(_a,         _d);                                                \
    glds16(_a + 65536, _d + 4096);                                         \
    glds16(_b,         _d + BBY);                                          \
    glds16(_b + 65536, _d + BBY + 4096);                                   \
  } while (0)

  // prologue: stage tile 0 into buf0, drain, sync
  STAGE(0, 0);
  __syncthreads();

  for (int t = 0; t < NT; ++t) {
    const char* Rb = lds + (t & 1) * BUFB;

    if (t < NT - 1) STAGE((t + 1) & 1, t + 1);   // prefetch next step

    i32x8 fa[4], fb[4];
#pragma unroll
    for (int fi = 0; fi < 4; ++fi) {
      const i32x4 v = *(const i32x4*)(Rb + offA[fi]);
      fa[fi][0] = v[0]; fa[fi][1] = v[1]; fa[fi][2] = v[2]; fa[fi][3] = v[3];
      fa[fi][4] = 0; fa[fi][5] = 0; fa[fi][6] = 0; fa[fi][7] = 0;
    }
#pragma unroll
    for (int fj = 0; fj < 4; ++fj) {
      const i32x4 v = *(const i32x4*)(Rb + offB[fj]);
      fb[fj][0] = v[0]; fb[fj][1] = v[1]; fb[fj][2] = v[2]; fb[fj][3] = v[3];
      fb[fj][4] = 0; fb[fj][5] = 0; fb[fj][6] = 0; fb[fj][7] = 0;
    }

#pragma unroll
    for (int fi = 0; fi < 4; ++fi)
#pragma unroll
      for (int fj = 0; fj < 4; ++fj)
        acc[fi][fj] = __builtin_amdgcn_mfma_scale_f32_16x16x128_f8f6f4(
            fa[fi], fb[fj], acc[fi][fj], 4, 4,          // cbsz=4 (fp4), blgp=4 (fp4)
            0, 0x7F7F7F7F, 0, 0x7F7F7F7F);              // uniform scales = 1.0

    // end of step: implicit vmcnt(0)+lgkmcnt(0)+barrier drains the prefetch
    __syncthreads();
  }
#undef STAGE

  // ---------- epilogue: per-row (max, sumexp, sum) + label gather ----------
  // C/D 16x16: col = lane&15, row = (lane>>4)*4 + reg  [verified m89/m91, R9/R10]
  const float inv = 0.0078125f;   // 1/128 (undo W pre-scale)
  const int row_base = m_tile * BM;
  const int col_base = n_tile * BN + wn * 64;

#pragma unroll
  for (int fi = 0; fi < 4; ++fi) {
#pragma unroll
    for (int r = 0; r < 4; ++r) {
      const int rt  = wm * 64 + fi * 16 + lhi * 4 + r;
      const int row = row_base + rt;
      const int lab = labels[row];
      const int rel = lab - col_base - l16;
#pragma unroll
      for (int fj = 0; fj < 4; ++fj) {
        if (rel == fj * 16) ly[row] = acc[fi][fj][r] * inv;   // static acc index
      }

      float mx = -INFINITY, sm = 0.f;
#pragma unroll
      for (int fj = 0; fj < 4; ++fj) {
        const bool v = (col_base + fj * 16 + l16) < N_CLS;
        const float x = acc[fi][fj][r] * inv;
        if (v) { mx = fmaxf(mx, x); sm += x; }
      }
#pragma unroll
      for (int d = 1; d < 16; d <<= 1) {
        mx = fmaxf(mx, __shfl_xor(mx, d));
        sm += __shfl_xor(sm, d);
      }
      float se = 0.f;
#pragma unroll
      for (int fj = 0; fj < 4; ++fj) {
        const bool v = (col_base + fj * 16 + l16) < N_CLS;
        if (v) se += __expf(acc[fi][fj][r] * inv - mx);
      }
#pragma unroll
      for (int d = 1; d < 16; d <<= 1) se += __shfl_xor(se, d);

      if (l16 == 0) { s_m[rt][wn] = mx; s_s[rt][wn] = se; s_t[rt][wn] = sm; }
    }
  }
  __syncthreads();
  if (tid < BM) {
    const float m0 = s_m[tid][0], m1 = s_m[tid][1];
    const float M = fmaxf(m0, m1);
    const float S = s_s[tid][0] * __expf(m0 - M) + s_s[tid][1] * __expf(m1 - M);
    const float T = s_t[tid][0] + s_t[tid][1];
    const size_t o = (size_t)n_tile * B_ROWS + row_base + tid;
    pm[o] = M; ps[o] = S; pt[o] = T;
  }
}

// ---------- final combine: GN partials per row -> loss ----------
__global__ void ce_reduce(const float* __restrict__ pm, const float* __restrict__ ps,
                          const float* __restrict__ pt, const float* __restrict__ ly,
                          float* __restrict__ out)
{
  const int tid = threadIdx.x;
  const int row = blockIdx.x * blockDim.x + tid;
  float M = -INFINITY, S = 0.f, T = 0.f;
  for (int nt = 0; nt < GN; ++nt) {
    const size_t o = (size_t)nt * B_ROWS + row;
    const float m = pm[o], s = ps[o], t = pt[o];
    const float Mn = fmaxf(M, m);
    S = S * __expf(M - Mn) + s * __expf(m - Mn);
    M = Mn;
    T += t;
  }
  const float lse = M + logf(S);
  float per = lse - 0.9f * ly[row] - 0.1f * (T * (1.0f / (float)N_CLS));
#pragma unroll
  for (int d = 1; d < 64; d <<= 1) per += __shfl_xor(per, d);
  __shared__ float red[4];
  if ((tid & 63) == 0) red[tid >> 6] = per;
  __syncthreads();
  if (tid == 0)
    atomicAdd(out, (red[0] + red[1] + red[2] + red[3]) * (1.0f / B_ROWS));
}

extern "C" void kernel_launch(void* const* d_in, const int* in_sizes, int n_in,
                              void* d_out, int out_size, void* d_ws, size_t ws_size,
                              hipStream_t stream)
{
  const float* E      = (const float*)d_in[0];
  const int*   labels = (const int*)  d_in[1];
  const float* W      = (const float*)d_in[2];
  float* out = (float*)d_out;

  char* ws = (char*)d_ws;
  unsigned char* Wq = (unsigned char*)ws;
  size_t off = (size_t)N_PAD * DKB;                // 51,511,296 B
  unsigned char* Eq = (unsigned char*)(ws + off);
  off += (size_t)B_ROWS * DKB;                     // + 2,097,152 B
  float* pm = (float*)(ws + off); off += (size_t)GN * B_ROWS * 4;
  float* ps = (float*)(ws + off); off += (size_t)GN * B_ROWS * 4;
  float* pt = (float*)(ws + off); off += (size_t)GN * B_ROWS * 4;
  float* ly = (float*)(ws + off);                  // total ~64 MB

  hipMemsetAsync(d_out, 0, sizeof(float), stream);
  conv_w_q4<<<dim3(2048), dim3(256), 0, stream>>>(W, Wq);
  conv_e_q4<<<dim3(512),  dim3(256), 0, stream>>>(E, Eq);
  gemm_ce<<<dim3(NWG), dim3(256), 0, stream>>>(Eq, Wq, labels, pm, ps, pt, ly);
  ce_reduce<<<dim3(B_ROWS / 256), dim3(256), 0, stream>>>(pm, ps, pt, ly, out);
}

// Round 17
// 408.555 us; speedup vs baseline: 7.2305x; 1.0280x over previous
//
#include <hip/hip_runtime.h>
#include <math.h>

#define B_ROWS 2048
#define D_K    2048
#define DKB    1024             // bytes per row at fp4 (0.5 B/elem)
#define N_CLS  50257
#define BM     128
#define BN     128
#define BKB    64               // K-BYTES per step = 128 elements
#define NT     16               // 2048 / 128 elements
#define GM     16               // 2048/128 m-tiles
#define GN     393              // ceil(50257/128) n-tiles
#define N_PAD  (GN * BN)        // 50304
#define NWG    (GM * GN)        // 6288 = 8*786 (bijective XCD swizzle)

// LDS: TRIPLE buffer, 16KB each (distance-2 prefetch, counted vmcnt(4)).
// Buffer b at b*16384: A [128 rows][64 B] at +0 (8KB), B at +8192 (8KB).
// 16-B slot swizzle within each 64-B row: position p = content_slot ^ ((row>>1)&3)
// (verified conflict-free R16). Stats (3KB) overlay buf0 after the loop.
#define BBY    8192
#define BUFB   16384

typedef __attribute__((ext_vector_type(4))) int   i32x4;
typedef __attribute__((ext_vector_type(8))) int   i32x8;
typedef __attribute__((ext_vector_type(4))) float f32x4;

typedef __attribute__((address_space(1))) const void as1cv;
typedef __attribute__((address_space(3))) void       as3v;

__device__ __forceinline__ void glds16(const void* g, void* l) {
  __builtin_amdgcn_global_load_lds((as1cv*)g, (as3v*)l, 16, 0, 0);
}

// ---- fp32 -> fp4 e2m1 (RNE on the 8-level grid), returns 4-bit code ----
__device__ __forceinline__ unsigned int q4(float x) {
  const unsigned int s = (x < 0.f) ? 8u : 0u;
  const float a = fabsf(x);
  unsigned int c;
  if      (a < 0.25f) c = 0;      // 0.0
  else if (a < 0.75f) c = 1;      // 0.5
  else if (a < 1.25f) c = 2;      // 1.0
  else if (a < 1.75f) c = 3;      // 1.5
  else if (a < 2.5f)  c = 4;      // 2.0
  else if (a < 3.5f)  c = 5;      // 3.0
  else if (a < 5.0f)  c = 6;      // 4.0
  else                c = 7;      // 6.0
  return s | c;
}

// ---------- W: fp32 -> fp4, scaled x128, zero-padded to N_PAD rows ----------
// element k -> byte k/2, nibble k&1 (little-endian packed, HW convention).
__global__ void conv_w_q4(const float* __restrict__ W, unsigned char* __restrict__ Wq) {
  const size_t NU = (size_t)N_PAD * D_K / 16;
  const size_t stride = (size_t)gridDim.x * blockDim.x;
  for (size_t u = (size_t)blockIdx.x * blockDim.x + threadIdx.x; u < NU; u += stride) {
    const size_t e = u * 16;
    unsigned long long pk = 0ull;
    if ((e >> 11) < (size_t)N_CLS) {
#pragma unroll
      for (int g = 0; g < 4; ++g) {
        const float4 a = *(const float4*)(W + e + g * 4);
        pk |= (unsigned long long)q4(a.x * 128.0f) << (16 * g + 0);
        pk |= (unsigned long long)q4(a.y * 128.0f) << (16 * g + 4);
        pk |= (unsigned long long)q4(a.z * 128.0f) << (16 * g + 8);
        pk |= (unsigned long long)q4(a.w * 128.0f) << (16 * g + 12);
      }
    }
    *(unsigned long long*)(Wq + u * 8) = pk;
  }
}

// ---------- E: fp32 -> fp4, unscaled ----------
__global__ void conv_e_q4(const float* __restrict__ E, unsigned char* __restrict__ Eq) {
  const size_t NU = (size_t)B_ROWS * D_K / 16;
  const size_t stride = (size_t)gridDim.x * blockDim.x;
  for (size_t u = (size_t)blockIdx.x * blockDim.x + threadIdx.x; u < NU; u += stride) {
    const size_t e = u * 16;
    unsigned long long pk = 0ull;
#pragma unroll
    for (int g = 0; g < 4; ++g) {
      const float4 a = *(const float4*)(E + e + g * 4);
      pk |= (unsigned long long)q4(a.x) << (16 * g + 0);
      pk |= (unsigned long long)q4(a.y) << (16 * g + 4);
      pk |= (unsigned long long)q4(a.z) << (16 * g + 8);
      pk |= (unsigned long long)q4(a.w) << (16 * g + 12);
    }
    *(unsigned long long*)(Eq + u * 8) = pk;
  }
}

// ---------- fused MX-fp4 GEMM + per-tile row stats ----------
// 128x128 tile, 4 waves (2x2), per-wave 64x64 via 4x4 mfma_scale 16x16x128
// (fp4: cbsz=blgp=4). f32x4 acc[4][4] = the never-spilled profile.
// 3-buffer LDS, distance-2 prefetch, counted vmcnt(4) across raw barriers:
// stage(t+1) gets a FULL step to land; stage(t+2) stays in flight.
__global__ __launch_bounds__(256) void gemm_ce(
    const unsigned char* __restrict__ Eq,
    const unsigned char* __restrict__ Wq,
    const int* __restrict__ labels,
    float* __restrict__ pm, float* __restrict__ ps, float* __restrict__ pt,
    float* __restrict__ ly)
{
  __shared__ __align__(16) char lds[3 * BUFB];
  // stats overlay (live only after the K-loop's final barrier):
  float (*s_m)[2] = (float (*)[2])(lds);
  float (*s_s)[2] = (float (*)[2])(lds + 1024);
  float (*s_t)[2] = (float (*)[2])(lds + 2048);

  const int tid  = threadIdx.x;
  const int wid  = tid >> 6;
  const int lane = tid & 63;
  const int wm   = wid >> 1;       // 0..1 -> 64-row block
  const int wn   = wid & 1;        // 0..1 -> 64-col block
  const int l16  = lane & 15;
  const int lhi  = lane >> 4;      // 0..3 -> 32-element k-chunk (16 B at fp4)

  // XCD-aware bijective swizzle (NWG = 8*786)
  const int bid     = blockIdx.x;
  const int logical = (bid & 7) * (NWG / 8) + (bid >> 3);
  const int n_tile  = logical / GM;   // 16 consecutive logicals share B panel
  const int m_tile  = logical % GM;

  // ---- staging: thread t, part q -> dest byte q*4096 + t*16
  //      row = q*64 + (t>>2); slot position = t&3
  //      content slot = (t&3) ^ ((row>>1)&3) = (t&3) ^ ((t>>3)&3)
  const int gsw  = (((tid & 3) ^ ((tid >> 3) & 3)) << 4);
  const int srow = tid >> 2;
  const unsigned char* Ag = Eq + (size_t)(m_tile * BM + srow) * DKB + gsw;
  const unsigned char* Bg = Wq + (size_t)(n_tile * BN + srow) * DKB + gsw;
  const int sdst = tid * 16;
  // +q -> +64 rows = +65536 B global; +K-step -> +64 B

  // ---- fragment read offsets: row R = base + l16 (64-B rows), content slot
  //      = lhi, position = lhi ^ ((R>>1)&3) = lhi ^ ((l16>>1)&3)
  const int rmsk = (l16 >> 1) & 3;
  const int psw  = (lhi ^ rmsk) << 4;
  int offA[4], offB[4];
#pragma unroll
  for (int fi = 0; fi < 4; ++fi)
    offA[fi] = (wm * 64 + fi * 16 + l16) * 64 + psw;
#pragma unroll
  for (int fj = 0; fj < 4; ++fj)
    offB[fj] = BBY + (wn * 64 + fj * 16 + l16) * 64 + psw;

  f32x4 acc[4][4] = {};

#define STAGE(BUF, TT)                                                     \
  do {                                                                     \
    const unsigned char* _a = Ag + (size_t)(TT) * BKB;                     \
    const unsigned char* _b = Bg + (size_t)(TT) * BKB;                     \
    char* _d = lds + (BUF) * BUFB + sdst;                                  \
    glds16(_a,         _d);                                                \
    glds16(_a + 65536, _d + 4096);                                         \
    glds16(_b,         _d + BBY);                                          \
    glds16(_b + 65536, _d + BBY + 4096);                                   \
  } while (0)

  // prologue: stage tiles 0,1 into bufs 0,1; drain tile 0 only (keep 1 in flight)
  STAGE(0, 0);
  STAGE(1, 1);
  asm volatile("s_waitcnt vmcnt(4)" ::: "memory");
  __builtin_amdgcn_sched_barrier(0);
  __builtin_amdgcn_s_barrier();
  __builtin_amdgcn_sched_barrier(0);

  int c0 = 0, c1 = 1, c2 = 2;
  for (int t = 0; t < NT; ++t) {
    const char* Rb = lds + c0 * BUFB;

    if (t < NT - 2) STAGE(c2, t + 2);   // distance-2 prefetch

    i32x8 fa[4], fb[4];
#pragma unroll
    for (int fi = 0; fi < 4; ++fi) {
      const i32x4 v = *(const i32x4*)(Rb + offA[fi]);
      fa[fi][0] = v[0]; fa[fi][1] = v[1]; fa[fi][2] = v[2]; fa[fi][3] = v[3];
      fa[fi][4] = 0; fa[fi][5] = 0; fa[fi][6] = 0; fa[fi][7] = 0;
    }
#pragma unroll
    for (int fj = 0; fj < 4; ++fj) {
      const i32x4 v = *(const i32x4*)(Rb + offB[fj]);
      fb[fj][0] = v[0]; fb[fj][1] = v[1]; fb[fj][2] = v[2]; fb[fj][3] = v[3];
      fb[fj][4] = 0; fb[fj][5] = 0; fb[fj][6] = 0; fb[fj][7] = 0;
    }

    __builtin_amdgcn_s_setprio(1);
#pragma unroll
    for (int fi = 0; fi < 4; ++fi)
#pragma unroll
      for (int fj = 0; fj < 4; ++fj)
        acc[fi][fj] = __builtin_amdgcn_mfma_scale_f32_16x16x128_f8f6f4(
            fa[fi], fb[fj], acc[fi][fj], 4, 4,          // cbsz=4, blgp=4 (e2m1)
            0, 0x7F7F7F7F, 0, 0x7F7F7F7F);              // uniform scales = 1.0
    __builtin_amdgcn_s_setprio(0);

    // end of step: drain stage(t+1) (older 4 loads); keep stage(t+2) in flight.
    if (t < NT - 2) asm volatile("s_waitcnt vmcnt(4)" ::: "memory");
    else            asm volatile("s_waitcnt vmcnt(0)" ::: "memory");
    __builtin_amdgcn_sched_barrier(0);
    __builtin_amdgcn_s_barrier();
    __builtin_amdgcn_sched_barrier(0);

    const int tmp = c0; c0 = c1; c1 = c2; c2 = tmp;
  }
#undef STAGE

  // ---------- epilogue: per-row (max, sumexp, sum) + label gather ----------
  // C/D 16x16: col = lane&15, row = (lane>>4)*4 + reg  [verified R9/R10/R16]
  const float inv = 0.0078125f;   // 1/128 (undo W pre-scale)
  const int row_base = m_tile * BM;
  const int col_base = n_tile * BN + wn * 64;

#pragma unroll
  for (int fi = 0; fi < 4; ++fi) {
#pragma unroll
    for (int r = 0; r < 4; ++r) {
      const int rt  = wm * 64 + fi * 16 + lhi * 4 + r;
      const int row = row_base + rt;
      const int lab = labels[row];
      const int rel = lab - col_base - l16;
#pragma unroll
      for (int fj = 0; fj < 4; ++fj) {
        if (rel == fj * 16) ly[row] = acc[fi][fj][r] * inv;   // static acc index
      }

      float mx = -INFINITY, sm = 0.f;
#pragma unroll
      for (int fj = 0; fj < 4; ++fj) {
        const bool v = (col_base + fj * 16 + l16) < N_CLS;
        const float x = acc[fi][fj][r] * inv;
        if (v) { mx = fmaxf(mx, x); sm += x; }
      }
#pragma unroll
      for (int d = 1; d < 16; d <<= 1) {
        mx = fmaxf(mx, __shfl_xor(mx, d));
        sm += __shfl_xor(sm, d);
      }
      float se = 0.f;
#pragma unroll
      for (int fj = 0; fj < 4; ++fj) {
        const bool v = (col_base + fj * 16 + l16) < N_CLS;
        if (v) se += __expf(acc[fi][fj][r] * inv - mx);
      }
#pragma unroll
      for (int d = 1; d < 16; d <<= 1) se += __shfl_xor(se, d);

      if (l16 == 0) { s_m[rt][wn] = mx; s_s[rt][wn] = se; s_t[rt][wn] = sm; }
    }
  }
  __syncthreads();
  if (tid < BM) {
    const float m0 = s_m[tid][0], m1 = s_m[tid][1];
    const float M = fmaxf(m0, m1);
    const float S = s_s[tid][0] * __expf(m0 - M) + s_s[tid][1] * __expf(m1 - M);
    const float T = s_t[tid][0] + s_t[tid][1];
    const size_t o = (size_t)n_tile * B_ROWS + row_base + tid;
    pm[o] = M; ps[o] = S; pt[o] = T;
  }
}

// ---------- final combine: GN partials per row -> loss ----------
__global__ void ce_reduce(const float* __restrict__ pm, const float* __restrict__ ps,
                          const float* __restrict__ pt, const float* __restrict__ ly,
                          float* __restrict__ out)
{
  const int tid = threadIdx.x;
  const int row = blockIdx.x * blockDim.x + tid;
  float M = -INFINITY, S = 0.f, T = 0.f;
  for (int nt = 0; nt < GN; ++nt) {
    const size_t o = (size_t)nt * B_ROWS + row;
    const float m = pm[o], s = ps[o], t = pt[o];
    const float Mn = fmaxf(M, m);
    S = S * __expf(M - Mn) + s * __expf(m - Mn);
    M = Mn;
    T += t;
  }
  const float lse = M + logf(S);
  float per = lse - 0.9f * ly[row] - 0.1f * (T * (1.0f / (float)N_CLS));
#pragma unroll
  for (int d = 1; d < 64; d <<= 1) per += __shfl_xor(per, d);
  __shared__ float red[4];
  if ((tid & 63) == 0) red[tid >> 6] = per;
  __syncthreads();
  if (tid == 0)
    atomicAdd(out, (red[0] + red[1] + red[2] + red[3]) * (1.0f / B_ROWS));
}

extern "C" void kernel_launch(void* const* d_in, const int* in_sizes, int n_in,
                              void* d_out, int out_size, void* d_ws, size_t ws_size,
                              hipStream_t stream)
{
  const float* E      = (const float*)d_in[0];
  const int*   labels = (const int*)  d_in[1];
  const float* W      = (const float*)d_in[2];
  float* out = (float*)d_out;

  char* ws = (char*)d_ws;
  unsigned char* Wq = (unsigned char*)ws;
  size_t off = (size_t)N_PAD * DKB;                // 51,511,296 B
  unsigned char* Eq = (unsigned char*)(ws + off);
  off += (size_t)B_ROWS * DKB;                     // + 2,097,152 B
  float* pm = (float*)(ws + off); off += (size_t)GN * B_ROWS * 4;
  float* ps = (float*)(ws + off); off += (size_t)GN * B_ROWS * 4;
  float* pt = (float*)(ws + off); off += (size_t)GN * B_ROWS * 4;
  float* ly = (float*)(ws + off);                  // total ~64 MB

  hipMemsetAsync(d_out, 0, sizeof(float), stream);
  conv_w_q4<<<dim3(2048), dim3(256), 0, stream>>>(W, Wq);
  conv_e_q4<<<dim3(512),  dim3(256), 0, stream>>>(E, Eq);
  gemm_ce<<<dim3(NWG), dim3(256), 0, stream>>>(Eq, Wq, labels, pm, ps, pt, ly);
  ce_reduce<<<dim3(B_ROWS / 256), dim3(256), 0, stream>>>(pm, ps, pt, ly, out);
}